// Round 5
// baseline (365.646 us; speedup 1.0000x reference)
//
#include <hip/hip_runtime.h>
#include <math.h>

// Shapes (compile-time)
#define BB 16
#define LL 28
#define RR 64
#define DD 512
#define NROLE 512           // role chunks: (r-pair, 64-d slice, e-half)
#define NEVT  256           // evt chunks: (b, 32-wide d range)
#define NBLK  (NROLE + NEVT)
#define NRED  136           // tail reducers: 128 div + 8 evt
#define NMLP  16
#define F4RR  65536         // DD*DD/4 : r-to-r stride in float4 units

// ---------------------------------------------------------------------------
// Single fused kernel, 768 blocks x 256 threads.
//  Block role by bid%3: rem in {0,1} -> role chunk rid = 2*(bid/3)+rem;
//  rem==2 -> evt chunk cid = bid/3. (Interleaved so CUs hold a uniform mix.)
//
//  Role chunk rid = rp<<4 | dI<<1 | eh (proven round-4 math):
//    Phase 1 builds G[2][64 d][16 b] (8 KB LDS), ONE barrier. Phase 2: wave h
//    owns k in [16h,16h+16) for BOTH r -> every WRT line fetched once per
//    block; 8-deep register float4 pipeline; 2-stage LDS combine; wave 0
//    stores partial [16 b][256 e] to part[rid].
//  Evt chunk: (b, 32-d range) -> evt_part (proven path).
//
//  Ticket tail (deadlock-free without residency assumptions: spinners only
//  exist after NBLK-NRED blocks COMPLETED, and NRED=136 < 256 CUs, so every
//  unstarted block always has a free slot even at 1 block/CU):
//   ticket ctrs[0]: last NRED arrivals spin until all NBLK published, then
//     128 blocks reduce part -> div_acc, 8 blocks reduce evt_part -> evt_acc.
//   ticket ctrs[1]: last NMLP arrivals spin until all NRED done, then run
//     the scorer MLP (one block per batch). Deterministic: block->work
//     mapping varies run to run, summation orders don't.
// ---------------------------------------------------------------------------
__global__ void __launch_bounds__(256, 2) kernel_fused(
    const float* __restrict__ logits,   // [B,L,R]
    const float* __restrict__ arg,      // [B,L,D]
    const float* __restrict__ WRT,      // [R,D,D]
    const float* __restrict__ WTT,      // [E,D,D]
    const float* __restrict__ evt_emb,  // [B,1,D]
    const int*   __restrict__ evt_type, // [B]
    const float* __restrict__ w1,       // [D,64]
    const float* __restrict__ b1,       // [64]
    const float* __restrict__ w2,       // [64,1]
    const float* __restrict__ b2,       // [1]
    float* __restrict__ part,           // [NROLE][16][256]
    float* __restrict__ evt_part,       // [NEVT][512]
    float* __restrict__ div_acc,        // [B*D]
    float* __restrict__ evt_acc,        // [B*D]
    unsigned* __restrict__ ctrs,        // [2], zeroed each launch
    float* __restrict__ out)            // [B,1]
{
    __shared__ float smem[8192];        // 32 KB, reused across phases
    __shared__ unsigned s_tick;
    const int t   = threadIdx.x;
    const int q   = blockIdx.x / 3;
    const int rem = blockIdx.x - 3 * q;

    if (rem != 2) {
        // -------- role chunk: (r-pair rp, d-slice d0, e-half eh) --------
        const int rid = 2 * q + rem;        // [0,512)
        const int rp  = rid >> 4;           // [0,32)
        const int d0  = ((rid >> 1) & 7) * 64;
        const int eh  = rid & 1;

        const float4* WBase = (const float4*)(WRT + ((size_t)(2 * rp) * DD + d0) * DD);

        const int e4    = t & 63;           // f4 col within e-half
        const int h     = t >> 6;           // wave id = k-quarter owner
        const int co    = eh * 64 + e4;     // f4 col within full row
        const int kbase = 16 * h;

        // Prefetch WRT batch 0 BEFORE phase 1.
        float4 w[8];
#pragma unroll
        for (int i = 0; i < 8; ++i)
            w[i] = WBase[(size_t)(kbase + i) * 128 + co];

        // Phase 1: G[rr][row][b], row = d-local in [0,64), b in [0,16).
        {
            const int b  = t >> 4;
            const int d4 = t & 15;          // float4 d-group (coalesced arg)
            const float4* ap = (const float4*)(arg) + (size_t)(b * LL) * 128 + (d0 >> 2) + d4;
            const float2* lp = (const float2*)(logits) + (size_t)(b * LL) * 32 + rp;
            float4 g0 = {0.f,0.f,0.f,0.f}, g1 = {0.f,0.f,0.f,0.f};
#pragma unroll 7
            for (int l = 0; l < LL; ++l) {
                const float4 av = ap[(size_t)l * 128];
                const float2 lg = lp[(size_t)l * 32];   // logits[b,l,2rp..2rp+1]
                g0.x = fmaf(lg.x, av.x, g0.x); g0.y = fmaf(lg.x, av.y, g0.y);
                g0.z = fmaf(lg.x, av.z, g0.z); g0.w = fmaf(lg.x, av.w, g0.w);
                g1.x = fmaf(lg.y, av.x, g1.x); g1.y = fmaf(lg.y, av.y, g1.y);
                g1.z = fmaf(lg.y, av.z, g1.z); g1.w = fmaf(lg.y, av.w, g1.w);
            }
            const int row = 4 * d4;
            smem[       (row + 0) * 16 + b] = g0.x;
            smem[       (row + 1) * 16 + b] = g0.y;
            smem[       (row + 2) * 16 + b] = g0.z;
            smem[       (row + 3) * 16 + b] = g0.w;
            smem[1024 + (row + 0) * 16 + b] = g1.x;
            smem[1024 + (row + 1) * 16 + b] = g1.y;
            smem[1024 + (row + 2) * 16 + b] = g1.z;
            smem[1024 + (row + 3) * 16 + b] = g1.w;
        }
        __syncthreads();

        // Phase 2: 4 macro-batches (rr = mb>>1, 8 k-rows each), reg dbuf.
        float4 acc[16];
#pragma unroll
        for (int i = 0; i < 16; ++i) acc[i] = make_float4(0.f, 0.f, 0.f, 0.f);

        for (int mb = 0; mb < 4; ++mb) {
            const int mbn = (mb + 1) & 3;            // wraps harmlessly at end
            const size_t nb = (size_t)(mbn >> 1) * F4RR;
            const int kn = kbase + (mbn & 1) * 8;
            float4 wn[8];
#pragma unroll
            for (int i = 0; i < 8; ++i)
                wn[i] = WBase[nb + (size_t)(kn + i) * 128 + co];

            const float* Gr = smem + (mb >> 1) * 1024;
            const int k0 = kbase + (mb & 1) * 8;
#pragma unroll
            for (int i = 0; i < 8; ++i) {
                const float* gp = Gr + (k0 + i) * 16;
                const float4 ga = ((const float4*)gp)[0];   // uniform b128 bcast
                const float4 gb = ((const float4*)gp)[1];
                const float4 gc = ((const float4*)gp)[2];
                const float4 gd = ((const float4*)gp)[3];
#define ACC(j, S) \
                acc[j].x = fmaf(S, w[i].x, acc[j].x); \
                acc[j].y = fmaf(S, w[i].y, acc[j].y); \
                acc[j].z = fmaf(S, w[i].z, acc[j].z); \
                acc[j].w = fmaf(S, w[i].w, acc[j].w);
                ACC(0,  ga.x) ACC(1,  ga.y) ACC(2,  ga.z) ACC(3,  ga.w)
                ACC(4,  gb.x) ACC(5,  gb.y) ACC(6,  gb.z) ACC(7,  gb.w)
                ACC(8,  gc.x) ACC(9,  gc.y) ACC(10, gc.z) ACC(11, gc.w)
                ACC(12, gd.x) ACC(13, gd.y) ACC(14, gd.z) ACC(15, gd.w)
#undef ACC
            }
#pragma unroll
            for (int i = 0; i < 8; ++i) w[i] = wn[i];
        }

        // 2-stage combine of the 4 k-quarter waves (G dead after barrier).
        __syncthreads();
        float4* cb = (float4*)smem;                  // 2048 f4 = 32 KB
        if (h >= 2) {
#pragma unroll
            for (int i = 0; i < 16; ++i)
                cb[(h - 2) * 1024 + i * 64 + e4] = acc[i];   // contig: no conflicts
        }
        __syncthreads();
        if (h < 2) {
#pragma unroll
            for (int i = 0; i < 16; ++i) {
                const float4 v = cb[h * 1024 + i * 64 + e4];
                acc[i].x += v.x; acc[i].y += v.y; acc[i].z += v.z; acc[i].w += v.w;
            }
        }
        __syncthreads();
        if (h == 1) {
#pragma unroll
            for (int i = 0; i < 16; ++i)
                cb[i * 64 + e4] = acc[i];
        }
        __syncthreads();
        if (h == 0) {
            float4* po = (float4*)part + (size_t)rid * 1024;  // [16][64] f4
#pragma unroll
            for (int i = 0; i < 16; ++i) {
                const float4 v = cb[i * 64 + e4];
                acc[i].x += v.x; acc[i].y += v.y; acc[i].z += v.z; acc[i].w += v.w;
                po[i * 64 + e4] = acc[i];
            }
        }
    } else {
        // ---------------- evt transform ----------------
        const int cid = q;              // [0,256)
        const int b   = cid >> 4;
        const int dc  = cid & 15;
        const int d0  = dc * 32;
        const int ty  = evt_type[b];
        const float* Wt = WTT + (size_t)ty * DD * DD;
        const int e4 = t & 127;
        const int s  = t >> 7;          // 2 d-streams
        float4 a = {0.f, 0.f, 0.f, 0.f};
#pragma unroll
        for (int db = 0; db < 32; db += 16) {
            float  em[8];
            float4 wv[8];
#pragma unroll
            for (int i = 0; i < 8; ++i) {
                const int d = d0 + db + s + 2 * i;
                em[i] = evt_emb[b * DD + d];                       // uniform
                wv[i] = ((const float4*)(Wt + (size_t)d * DD))[e4];
            }
#pragma unroll
            for (int i = 0; i < 8; ++i) {
                a.x = fmaf(em[i], wv[i].x, a.x);
                a.y = fmaf(em[i], wv[i].y, a.y);
                a.z = fmaf(em[i], wv[i].z, a.z);
                a.w = fmaf(em[i], wv[i].w, a.w);
            }
        }
        float4* sm4 = (float4*)smem;
        if (s == 1) sm4[e4] = a;
        __syncthreads();
        if (s == 0) {
            const float4 q4 = sm4[e4];
            a.x += q4.x; a.y += q4.y; a.z += q4.z; a.w += q4.w;
            ((float4*)evt_part)[(size_t)cid * 128 + e4] = a;
        }
    }

    // ------------------- ticket tail 1: reduction -------------------
    __threadfence();                    // release partials (device scope)
    __syncthreads();
    if (t == 0)
        s_tick = __hip_atomic_fetch_add(&ctrs[0], 1u, __ATOMIC_RELEASE,
                                        __HIP_MEMORY_SCOPE_AGENT);
    __syncthreads();
    {
        const unsigned tick = s_tick;
        if (tick < (unsigned)(NBLK - NRED)) return;   // early blocks retire
        const int ridx = (int)tick - (NBLK - NRED);   // [0,NRED)
        if (t == 0) {
            while (__hip_atomic_load(&ctrs[0], __ATOMIC_ACQUIRE,
                                     __HIP_MEMORY_SCOPE_AGENT) < (unsigned)NBLK)
                __builtin_amdgcn_s_sleep(8);
        }
        __syncthreads();
        __threadfence();                // acquire: see all partials

        if (ridx < 128) {
            // div: block owns 16 f4 outputs o4 = ridx*16+oo (o4 = b*128+e4).
            // For a given e4, 256 of the 512 partials contribute (matching
            // e-half eh = e4>>6): rid = 2*m + eh, m in [0,256).
            float4* sred = (float4*)smem;             // 4 KB
            const int oo = t & 15;
            const int pg = t >> 4;                    // 16 groups x 16 m's
            const int o4 = ridx * 16 + oo;
            const int b  = o4 >> 7;
            const int e4g = o4 & 127;
            const int eh = e4g >> 6;
            const int ec = e4g & 63;
            const float4* p4 = (const float4*)part;
            float4 s = {0.f, 0.f, 0.f, 0.f};
#pragma unroll 8
            for (int i = 0; i < 16; ++i) {
                const int m = pg * 16 + i;
                const float4 v = p4[(size_t)(2 * m + eh) * 1024 + b * 64 + ec];
                s.x += v.x; s.y += v.y; s.z += v.z; s.w += v.w;
            }
            sred[pg * 16 + oo] = s;
            __syncthreads();
            if (t < 16) {
                float4 tot = sred[t];
#pragma unroll
                for (int g = 1; g < 16; ++g) {
                    const float4 v = sred[g * 16 + t];
                    tot.x += v.x; tot.y += v.y; tot.z += v.z; tot.w += v.w;
                }
                ((float4*)div_acc)[ridx * 16 + t] = tot;
            }
        } else {
            // evt: 8 blocks cover 2048 f4 outputs, sum 16 d-chunks each.
            const int o4 = (ridx - 128) * 256 + t;    // [0,2048)
            const int b  = o4 >> 7;
            const int el = o4 & 127;
            const float4* e4p = (const float4*)evt_part;
            float4 s = {0.f, 0.f, 0.f, 0.f};
#pragma unroll
            for (int dc = 0; dc < 16; ++dc) {
                const float4 v = e4p[(size_t)(b * 16 + dc) * 128 + el];
                s.x += v.x; s.y += v.y; s.z += v.z; s.w += v.w;
            }
            ((float4*)evt_acc)[o4] = s;
        }
    }

    // ------------------- ticket tail 2: MLP -------------------
    __threadfence();
    __syncthreads();
    if (t == 0)
        s_tick = __hip_atomic_fetch_add(&ctrs[1], 1u, __ATOMIC_RELEASE,
                                        __HIP_MEMORY_SCOPE_AGENT);
    __syncthreads();
    {
        const unsigned tick2 = s_tick;
        if (tick2 < (unsigned)(NRED - NMLP)) return;
        const int b = (int)tick2 - (NRED - NMLP);     // [0,16): batch index
        if (t == 0) {
            while (__hip_atomic_load(&ctrs[1], __ATOMIC_ACQUIRE,
                                     __HIP_MEMORY_SCOPE_AGENT) < (unsigned)NRED)
                __builtin_amdgcn_s_sleep(8);
        }
        __syncthreads();
        __threadfence();

        // graph=(div+evt)/2 ; h=relu(graph@w1+b1) ; out=sigmoid(h@w2+b2)
        const int j  = t & 63;
        const int dq = t >> 6;
        float hp = 0.f;
#pragma unroll 8
        for (int i = 0; i < 128; ++i) {
            const int d = dq * 128 + i;
            const float g = (div_acc[b * DD + d] + evt_acc[b * DD + d]) * 0.5f;
            hp = fmaf(g, w1[d * 64 + j], hp);
        }
        smem[t] = hp;
        __syncthreads();
        if (t < 64) {
            float hh = b1[j] + smem[j] + smem[64 + j] + smem[128 + j] + smem[192 + j];
            hh = fmaxf(hh, 0.f);
            float v = hh * w2[j];
#pragma unroll
            for (int off = 32; off > 0; off >>= 1) v += __shfl_down(v, off, 64);
            if (j == 0) out[b] = 1.f / (1.f + expf(-(v + b2[0])));
        }
    }
}

// ---------------------------------------------------------------------------
extern "C" void kernel_launch(void* const* d_in, const int* in_sizes, int n_in,
                              void* d_out, int out_size, void* d_ws, size_t ws_size,
                              hipStream_t stream) {
    const float* logits   = (const float*)d_in[0];
    const float* evt_emb  = (const float*)d_in[1];
    const float* arg_emb  = (const float*)d_in[2];
    // d_in[3] arg_padding_num cancels algebraically; unused
    const int*   evt_type = (const int*)d_in[4];
    const float* WRT      = (const float*)d_in[5];
    const float* WTT      = (const float*)d_in[6];
    const float* w1       = (const float*)d_in[7];
    const float* b1       = (const float*)d_in[8];
    const float* w2       = (const float*)d_in[9];
    const float* b2       = (const float*)d_in[10];
    float* out = (float*)d_out;

    float* part     = (float*)d_ws;                      // 512*4096 floats = 8.39 MB
    float* evt_part = part + (size_t)NROLE * 4096;       // 256*512 floats = 512 KB
    float* div_acc  = evt_part + (size_t)NEVT * DD;      // 8192 floats
    float* evt_acc  = div_acc + BB * DD;                 // 8192 floats
    unsigned* ctrs  = (unsigned*)(evt_acc + BB * DD);    // 2 uints

    hipMemsetAsync(ctrs, 0, 2 * sizeof(unsigned), stream);
    hipLaunchKernelGGL(kernel_fused, dim3(NBLK), dim3(256), 0, stream,
                       logits, arg_emb, WRT, WTT, evt_emb, evt_type,
                       w1, b1, w2, b2, part, evt_part, div_acc, evt_acc,
                       ctrs, out);
}

// Round 6
// 147.078 us; speedup vs baseline: 2.4861x; 2.4861x over previous
//
#include <hip/hip_runtime.h>
#include <math.h>

// Shapes (compile-time)
#define BB 16
#define LL 28
#define RR 64
#define DD 512
#define NROLE 512           // role chunks: (r-pair, 64-d slice, e-half)
#define NEVT  256           // evt chunks: (b, 32-wide d range)
#define F4RR  65536         // DD*DD/4 : r-to-r stride in float4 units

// ---------------------------------------------------------------------------
// Kernel A (fused main). Round-5 lesson: in-kernel global sync (ticket tail)
// costs ~250us on this 8-XCD part (device-scope fences + coherent polling =
// L2 writeback storms). Two plain dispatches are the fast structure.
//
//  bid < NROLE: role chunk rid = rp<<4 | dI<<1 | eh:
//    rp in [0,32): r-pair {2rp,2rp+1}; dI in [0,8): d-slice d0=64*dI;
//    eh in {0,1}: e-half (256 output cols). e-split adds NO WRT duplication
//    (disjoint columns) and NO extra partial traffic -> pure parallelism.
//    Phase 1 builds G[2][64 d][16 b] (8 KB LDS) reusing arg float4 loads
//    (logits float2 per r-pair). ONE barrier.
//    Phase 2: wave h (4 waves) owns k in [16h,16h+16) for BOTH r -> every
//    WRT line fetched once per block; 4 macro-batches of 8 rows, 8-deep
//    register float4 pipeline, acc[16 b] x f4. 2-stage LDS combine of the
//    4 waves; wave 0 stores partial [16 b][256 e] to part[rid].
//  bid >= NROLE: evt chunk (b, 32-d range) -> evt_part (proven path).
//
//  __launch_bounds__(256, 3): VGPR 76 <= 170, LDS 3x32KB = 96KB <= 160KB ->
//  all 768 blocks co-resident (12 waves/CU), fixing the round-3/4 latency
//  starvation (Occ 6%, VALUBusy 12%) without touching proven math.
// ---------------------------------------------------------------------------
__global__ void __launch_bounds__(256, 3) kernel_a(
    const float* __restrict__ logits,   // [B,L,R]
    const float* __restrict__ arg,      // [B,L,D]
    const float* __restrict__ WRT,      // [R,D,D]
    const float* __restrict__ WTT,      // [E,D,D]
    const float* __restrict__ evt_emb,  // [B,1,D]
    const int*   __restrict__ evt_type, // [B]
    float* __restrict__ part,           // [NROLE][16][256]
    float* __restrict__ evt_part)       // [NEVT][512]
{
    __shared__ float smem[8192];        // 32 KB (G 8KB, combine 32KB)
    const int t   = threadIdx.x;
    const int bid = blockIdx.x;

    if (bid < NROLE) {
        // -------- role chunk: (r-pair rp, d-slice d0, e-half eh) --------
        const int rid = bid;
        const int rp  = rid >> 4;           // [0,32)
        const int d0  = ((rid >> 1) & 7) * 64;
        const int eh  = rid & 1;

        const float4* WBase = (const float4*)(WRT + ((size_t)(2 * rp) * DD + d0) * DD);

        const int e4    = t & 63;           // f4 col within e-half
        const int h     = t >> 6;           // wave id = k-quarter owner
        const int co    = eh * 64 + e4;     // f4 col within full row
        const int kbase = 16 * h;

        // Prefetch WRT batch 0 (this wave's k-rows 0..7 of r0) BEFORE phase 1.
        float4 w[8];
#pragma unroll
        for (int i = 0; i < 8; ++i)
            w[i] = WBase[(size_t)(kbase + i) * 128 + co];

        // Phase 1: G[rr][row][b], row = d-local in [0,64), b in [0,16).
        {
            const int b  = t >> 4;
            const int d4 = t & 15;          // float4 d-group (coalesced arg)
            const float4* ap = (const float4*)(arg) + (size_t)(b * LL) * 128 + (d0 >> 2) + d4;
            const float2* lp = (const float2*)(logits) + (size_t)(b * LL) * 32 + rp;
            float4 g0 = {0.f,0.f,0.f,0.f}, g1 = {0.f,0.f,0.f,0.f};
#pragma unroll 7
            for (int l = 0; l < LL; ++l) {
                const float4 av = ap[(size_t)l * 128];
                const float2 lg = lp[(size_t)l * 32];   // logits[b,l,2rp..2rp+1]
                g0.x = fmaf(lg.x, av.x, g0.x); g0.y = fmaf(lg.x, av.y, g0.y);
                g0.z = fmaf(lg.x, av.z, g0.z); g0.w = fmaf(lg.x, av.w, g0.w);
                g1.x = fmaf(lg.y, av.x, g1.x); g1.y = fmaf(lg.y, av.y, g1.y);
                g1.z = fmaf(lg.y, av.z, g1.z); g1.w = fmaf(lg.y, av.w, g1.w);
            }
            const int row = 4 * d4;
            smem[       (row + 0) * 16 + b] = g0.x;
            smem[       (row + 1) * 16 + b] = g0.y;
            smem[       (row + 2) * 16 + b] = g0.z;
            smem[       (row + 3) * 16 + b] = g0.w;
            smem[1024 + (row + 0) * 16 + b] = g1.x;
            smem[1024 + (row + 1) * 16 + b] = g1.y;
            smem[1024 + (row + 2) * 16 + b] = g1.z;
            smem[1024 + (row + 3) * 16 + b] = g1.w;
        }
        __syncthreads();

        // Phase 2: 4 macro-batches (rr = mb>>1, 8 k-rows each), reg dbuf.
        float4 acc[16];
#pragma unroll
        for (int i = 0; i < 16; ++i) acc[i] = make_float4(0.f, 0.f, 0.f, 0.f);

        for (int mb = 0; mb < 4; ++mb) {
            const int mbn = (mb + 1) & 3;            // wraps harmlessly at end
            const size_t nb = (size_t)(mbn >> 1) * F4RR;
            const int kn = kbase + (mbn & 1) * 8;
            float4 wn[8];
#pragma unroll
            for (int i = 0; i < 8; ++i)
                wn[i] = WBase[nb + (size_t)(kn + i) * 128 + co];

            const float* Gr = smem + (mb >> 1) * 1024;
            const int k0 = kbase + (mb & 1) * 8;
#pragma unroll
            for (int i = 0; i < 8; ++i) {
                const float* gp = Gr + (k0 + i) * 16;
                const float4 ga = ((const float4*)gp)[0];   // uniform b128 bcast
                const float4 gb = ((const float4*)gp)[1];
                const float4 gc = ((const float4*)gp)[2];
                const float4 gd = ((const float4*)gp)[3];
#define ACC(j, S) \
                acc[j].x = fmaf(S, w[i].x, acc[j].x); \
                acc[j].y = fmaf(S, w[i].y, acc[j].y); \
                acc[j].z = fmaf(S, w[i].z, acc[j].z); \
                acc[j].w = fmaf(S, w[i].w, acc[j].w);
                ACC(0,  ga.x) ACC(1,  ga.y) ACC(2,  ga.z) ACC(3,  ga.w)
                ACC(4,  gb.x) ACC(5,  gb.y) ACC(6,  gb.z) ACC(7,  gb.w)
                ACC(8,  gc.x) ACC(9,  gc.y) ACC(10, gc.z) ACC(11, gc.w)
                ACC(12, gd.x) ACC(13, gd.y) ACC(14, gd.z) ACC(15, gd.w)
#undef ACC
            }
#pragma unroll
            for (int i = 0; i < 8; ++i) w[i] = wn[i];
        }

        // 2-stage combine of the 4 k-quarter waves (G dead after barrier).
        __syncthreads();
        float4* cb = (float4*)smem;                  // 2048 f4 = 32 KB
        if (h >= 2) {
#pragma unroll
            for (int i = 0; i < 16; ++i)
                cb[(h - 2) * 1024 + i * 64 + e4] = acc[i];   // contig: no conflicts
        }
        __syncthreads();
        if (h < 2) {
#pragma unroll
            for (int i = 0; i < 16; ++i) {
                const float4 v = cb[h * 1024 + i * 64 + e4];
                acc[i].x += v.x; acc[i].y += v.y; acc[i].z += v.z; acc[i].w += v.w;
            }
        }
        __syncthreads();
        if (h == 1) {
#pragma unroll
            for (int i = 0; i < 16; ++i)
                cb[i * 64 + e4] = acc[i];
        }
        __syncthreads();
        if (h == 0) {
            float4* po = (float4*)part + (size_t)rid * 1024;  // [16][64] f4
#pragma unroll
            for (int i = 0; i < 16; ++i) {
                const float4 v = cb[i * 64 + e4];
                acc[i].x += v.x; acc[i].y += v.y; acc[i].z += v.z; acc[i].w += v.w;
                po[i * 64 + e4] = acc[i];
            }
        }
    } else {
        // ---------------- evt transform ----------------
        const int cid = bid - NROLE;    // [0,256)
        const int b   = cid >> 4;
        const int dc  = cid & 15;
        const int d0  = dc * 32;
        const int ty  = evt_type[b];
        const float* Wt = WTT + (size_t)ty * DD * DD;
        const int e4 = t & 127;
        const int s  = t >> 7;          // 2 d-streams
        float4 a = {0.f, 0.f, 0.f, 0.f};
#pragma unroll
        for (int db = 0; db < 32; db += 16) {
            float  em[8];
            float4 wv[8];
#pragma unroll
            for (int i = 0; i < 8; ++i) {
                const int d = d0 + db + s + 2 * i;
                em[i] = evt_emb[b * DD + d];                       // uniform
                wv[i] = ((const float4*)(Wt + (size_t)d * DD))[e4];
            }
#pragma unroll
            for (int i = 0; i < 8; ++i) {
                a.x = fmaf(em[i], wv[i].x, a.x);
                a.y = fmaf(em[i], wv[i].y, a.y);
                a.z = fmaf(em[i], wv[i].z, a.z);
                a.w = fmaf(em[i], wv[i].w, a.w);
            }
        }
        float4* sm4 = (float4*)smem;
        if (s == 1) sm4[e4] = a;
        __syncthreads();
        if (s == 0) {
            const float4 q4 = sm4[e4];
            a.x += q4.x; a.y += q4.y; a.z += q4.z; a.w += q4.w;
            ((float4*)evt_part)[(size_t)cid * 128 + e4] = a;
        }
    }
}

// ---------------------------------------------------------------------------
// Fused tail: per-batch reduction of part (512 partials, 256 per e-half) +
// evt_part (16 chunks), then the scorer MLP — one block per batch b, 1024
// threads. Deterministic fixed-order reduction, no atomics.
// ---------------------------------------------------------------------------
__global__ void __launch_bounds__(1024) kernel_tail(
    const float* __restrict__ part,     // [NROLE][16][256]
    const float* __restrict__ evt_part, // [NEVT][512]
    const float* __restrict__ w1,       // [D,64]
    const float* __restrict__ b1,       // [64]
    const float* __restrict__ w2,       // [64,1]
    const float* __restrict__ b2,       // [1]
    float* __restrict__ out)            // [B,1]
{
    __shared__ float4 sm4[2048];        // 32 KB: [0,1024) div, [1024,2048) evt
    __shared__ float  gsm[512];         // graph embedding for this b
    __shared__ float  hred[1024];       // MLP partial reduce
    const int b  = blockIdx.x;
    const int t  = threadIdx.x;
    const int e4 = t & 127;             // f4 col in full 512-e space
    const int g  = t >> 7;              // 8 groups
    const int eh = e4 >> 6;             // which e-half partials to read
    const int ec = e4 & 63;             // f4 col within the half

    // div: for this e4's half, sum 256 (rp,dI) partials (group sums 32)
    const float4* p4  = (const float4*)part;
    const float4* e4p = (const float4*)evt_part;
    float4 s = {0.f, 0.f, 0.f, 0.f};
#pragma unroll
    for (int i = 0; i < 32; ++i) {
        const int m = g * 32 + i;                     // (rp,dI) linear index
        const float4 v = p4[(size_t)(2 * m + eh) * 1024 + b * 64 + ec];
        s.x += v.x; s.y += v.y; s.z += v.z; s.w += v.w;
    }
    sm4[g * 128 + e4] = s;
    // evt: sum 16 d-chunks (group sums 2)
    float4 es = {0.f, 0.f, 0.f, 0.f};
#pragma unroll
    for (int i = 0; i < 2; ++i) {
        const int dc = g * 2 + i;
        const float4 v = e4p[(size_t)(b * 16 + dc) * 128 + e4];
        es.x += v.x; es.y += v.y; es.z += v.z; es.w += v.w;
    }
    sm4[1024 + g * 128 + e4] = es;
    __syncthreads();

    // combine groups, form graph = (div + evt) * 0.5
    if (t < 128) {
        float4 dv = {0.f,0.f,0.f,0.f}, ev = {0.f,0.f,0.f,0.f};
#pragma unroll
        for (int q = 0; q < 8; ++q) {
            const float4 a = sm4[q * 128 + t];
            const float4 c = sm4[1024 + q * 128 + t];
            dv.x += a.x; dv.y += a.y; dv.z += a.z; dv.w += a.w;
            ev.x += c.x; ev.y += c.y; ev.z += c.z; ev.w += c.w;
        }
        float4 gr;
        gr.x = (dv.x + ev.x) * 0.5f;
        gr.y = (dv.y + ev.y) * 0.5f;
        gr.z = (dv.z + ev.z) * 0.5f;
        gr.w = (dv.w + ev.w) * 0.5f;
        ((float4*)gsm)[t] = gr;
    }
    __syncthreads();

    // MLP: h = relu(graph@w1 + b1) ; out = sigmoid(h@w2 + b2)
    {
        const int j  = t & 63;
        const int dq = t >> 6;          // 16 d-groups of 32
        float hp = 0.f;
#pragma unroll 8
        for (int i = 0; i < 32; ++i) {
            const int d = dq * 32 + i;
            hp = fmaf(gsm[d], w1[d * 64 + j], hp);
        }
        hred[t] = hp;
    }
    __syncthreads();
    if (t < 64) {
        float hh = b1[t];
#pragma unroll
        for (int q = 0; q < 16; ++q) hh += hred[q * 64 + t];
        hh = fmaxf(hh, 0.f);
        float v = hh * w2[t];
#pragma unroll
        for (int off = 32; off > 0; off >>= 1) v += __shfl_down(v, off, 64);
        if (t == 0) out[b] = 1.f / (1.f + expf(-(v + b2[0])));
    }
}

// ---------------------------------------------------------------------------
extern "C" void kernel_launch(void* const* d_in, const int* in_sizes, int n_in,
                              void* d_out, int out_size, void* d_ws, size_t ws_size,
                              hipStream_t stream) {
    const float* logits   = (const float*)d_in[0];
    const float* evt_emb  = (const float*)d_in[1];
    const float* arg_emb  = (const float*)d_in[2];
    // d_in[3] arg_padding_num cancels algebraically; unused
    const int*   evt_type = (const int*)d_in[4];
    const float* WRT      = (const float*)d_in[5];
    const float* WTT      = (const float*)d_in[6];
    const float* w1       = (const float*)d_in[7];
    const float* b1       = (const float*)d_in[8];
    const float* w2       = (const float*)d_in[9];
    const float* b2       = (const float*)d_in[10];
    float* out = (float*)d_out;

    float* part     = (float*)d_ws;                      // 512*4096 floats = 8.39 MB
    float* evt_part = part + (size_t)NROLE * 4096;       // 256*512 floats = 512 KB

    hipLaunchKernelGGL(kernel_a, dim3(NROLE + NEVT), dim3(256), 0, stream,
                       logits, arg_emb, WRT, WTT, evt_emb, evt_type, part, evt_part);
    hipLaunchKernelGGL(kernel_tail, dim3(BB), dim3(1024), 0, stream,
                       part, evt_part, w1, b1, w2, b2, out);
}